// Round 17
// baseline (122.782 us; speedup 1.0000x reference)
//
#include <hip/hip_runtime.h>
#include <math.h>

#define NSPK 2048
#define GUT  10
#define DIM  512
#define NG   (NSPK*GUT)

#define BM 256
#define BN 128
#define BK 64
#define NCB (NSPK/BN)   // 16 column blocks
#define NHB (NCB*2)     // 32 column half-blocks (64 cols each)
#define NRB (NG/BM)     // 80 row blocks
#define NKC (DIM/BK)    // 8 K-iterations
#define K3B (NG/256)    // 80 k3 blocks
#define LBUF 24576      // 24 KB per LDS buffer: A[256][64]=16K + B[128][64]=8K

typedef __attribute__((ext_vector_type(4))) int int4v;

__device__ inline void gload_lds16(const void* g, void* l) {
  __builtin_amdgcn_global_load_lds(
      (const __attribute__((address_space(1))) void*)g,
      (__attribute__((address_space(3))) void*)l, 16, 0, 0);
}

__device__ __forceinline__ float mergesum(float a, float b, int mask, bool bsel) {
  const float ss = bsel ? a : b;
  const float sk = bsel ? b : a;
  return sk + __shfl_xor(ss, mask);
}
__device__ inline unsigned pack4i8(float a, float b, float c, float d, float qs) {
  const int q0 = (int)rintf(a * qs) & 255, q1 = (int)rintf(b * qs) & 255;
  const int q2 = (int)rintf(c * qs) & 255, q3 = (int)rintf(d * qs) & 255;
  return (unsigned)q0 | ((unsigned)q1 << 8) | ((unsigned)q2 << 16) | ((unsigned)q3 << 24);
}

// ---------------- Kernel 1: 4 speakers/block (1 wave each); multi-value butterfly ----------------
__global__ __launch_bounds__(256) void k1_prep(const float* __restrict__ x,
    unsigned char* __restrict__ xn8, unsigned char* __restrict__ cn8,
    float* __restrict__ xs, float* __restrict__ cs, float* __restrict__ diag)
{
  const int n = blockIdx.x * 4 + (threadIdx.x >> 6);
  const int l = threadIdx.x & 63;
  const float* xb = x + (size_t)n * GUT * DIM + l * 8;

  float4 xa[GUT], xc[GUT];
#pragma unroll
  for (int g = 0; g < GUT; ++g) {
    xa[g] = *reinterpret_cast<const float4*>(xb + g * DIM);
    xc[g] = *reinterpret_cast<const float4*>(xb + g * DIM + 4);
  }
  float s0=0,s1=0,s2=0,s3=0,s4=0,s5=0,s6=0,s7=0;
#pragma unroll
  for (int g = 0; g < GUT; ++g) {
    s0 += xa[g].x; s1 += xa[g].y; s2 += xa[g].z; s3 += xa[g].w;
    s4 += xc[g].x; s5 += xc[g].y; s6 += xc[g].z; s7 += xc[g].w;
  }
  float P[GUT], D[GUT];
  float mxa = 0.f;
#pragma unroll
  for (int g = 0; g < GUT; ++g) {
    P[g] = xa[g].x*xa[g].x + xa[g].y*xa[g].y + xa[g].z*xa[g].z + xa[g].w*xa[g].w
         + xc[g].x*xc[g].x + xc[g].y*xc[g].y + xc[g].z*xc[g].z + xc[g].w*xc[g].w;
    D[g] = xa[g].x*s0 + xa[g].y*s1 + xa[g].z*s2 + xa[g].w*s3
         + xc[g].x*s4 + xc[g].y*s5 + xc[g].z*s6 + xc[g].w*s7;
    const float m1 = fmaxf(fmaxf(fabsf(xa[g].x), fabsf(xa[g].y)), fmaxf(fabsf(xa[g].z), fabsf(xa[g].w)));
    const float m2 = fmaxf(fmaxf(fabsf(xc[g].x), fabsf(xc[g].y)), fmaxf(fabsf(xc[g].z), fabsf(xc[g].w)));
    mxa = fmaxf(mxa, fmaxf(m1, m2));
  }
  float S = s0*s0+s1*s1+s2*s2+s3*s3+s4*s4+s5*s5+s6*s6+s7*s7;
  float ms = fmaxf(fmaxf(fmaxf(fabsf(s0),fabsf(s1)),fmaxf(fabsf(s2),fabsf(s3))),
                   fmaxf(fmaxf(fabsf(s4),fabsf(s5)),fmaxf(fabsf(s6),fabsf(s7))));

  const bool b0 = l & 1, b1 = l & 2, b2 = l & 4, b3 = l & 8, b4 = l & 16;
  float P01 = mergesum(P[0], P[1], 1, b0);
  float P23 = mergesum(P[2], P[3], 1, b0);
  float P45 = mergesum(P[4], P[5], 1, b0);
  float P67 = mergesum(P[6], P[7], 1, b0);
  float P89 = mergesum(P[8], P[9], 1, b0);
  float D01 = mergesum(D[0], D[1], 1, b0);
  float D23 = mergesum(D[2], D[3], 1, b0);
  float D45 = mergesum(D[4], D[5], 1, b0);
  float D67 = mergesum(D[6], D[7], 1, b0);
  float D89 = mergesum(D[8], D[9], 1, b0);
  S += __shfl_xor(S, 1);
  float PA1 = mergesum(P01, P23, 2, b1);
  float PB1 = mergesum(P45, P67, 2, b1);
  float DA1 = mergesum(D01, D23, 2, b1);
  float DB1 = mergesum(D45, D67, 2, b1);
  P89 += __shfl_xor(P89, 2); D89 += __shfl_xor(D89, 2); S += __shfl_xor(S, 2);
  float PA = mergesum(PA1, PB1, 4, b2);
  float DA = mergesum(DA1, DB1, 4, b2);
  P89 += __shfl_xor(P89, 4); D89 += __shfl_xor(D89, 4); S += __shfl_xor(S, 4);
  float PX = mergesum(PA, P89, 8, b3);
  float DX = mergesum(DA, D89, 8, b3);
  S += __shfl_xor(S, 8);
  float V = mergesum(PX, DX, 16, b4);
  S += __shfl_xor(S, 16);
  V += __shfl_xor(V, 32);
  S += __shfl_xor(S, 32);

#pragma unroll
  for (int m = 1; m < 64; m <<= 1) mxa = fmaxf(mxa, __shfl_xor(mxa, m));
#pragma unroll
  for (int m = 1; m < 64; m <<= 1) ms = fmaxf(ms, __shfl_xor(ms, m));

  const float pdv = __shfl(V, l + 16);

  const float qs = 127.0f / mxa;
#pragma unroll
  for (int g = 0; g < GUT; ++g) {
    uint2 v; v.x = pack4i8(xa[g].x, xa[g].y, xa[g].z, xa[g].w, qs);
             v.y = pack4i8(xc[g].x, xc[g].y, xc[g].z, xc[g].w, qs);
    reinterpret_cast<uint2*>(xn8)[((size_t)n * GUT + g) * 64 + l] = v;
  }
  const float qsc = 127.0f / ms;
  {
    uint2 cp; cp.x = pack4i8(s0, s1, s2, s3, qsc); cp.y = pack4i8(s4, s5, s6, s7, qsc);
    reinterpret_cast<uint2*>(cn8)[n * 64 + l] = cp;
  }

  if (l < GUT) {
    const float psq = V, pd = pdv;
    const float dxe = (pd - psq) * (1.0f / (GUT - 1));
    float ne2 = (S - 2.f * pd + psq) * (1.0f / ((GUT - 1) * (GUT - 1)));
    ne2 = fmaxf(ne2, 0.f);
    const float rn = fmaxf(sqrtf(psq), 1e-8f);
    diag[n * GUT + l] = dxe / (rn * fmaxf(sqrtf(ne2), 1e-8f));
    xs[n * GUT + l] = mxa / (127.0f * rn);
  }
  if (l == 0) {
    const float cnorm  = sqrtf(S) * (1.0f / GUT);
    const float cscale = (1.0f / GUT) / fmaxf(cnorm, 1e-8f);
    cs[n] = cscale * ms * (1.0f / 127.0f);
  }
}

// ---------------- Kernel 2 (template): BM=256 8-wave dbuf (round-14, 42.2us) ----------------
// V=0: full (real output). V=1: NOEPI ablation probe -- identical main loop, epilogue
// replaced by DCE-proof acc sum -> dummy store. Probe timing read via headline diff.
template<int V>
__global__ __launch_bounds__(512, 4) void k2_mfma(
    const unsigned char* __restrict__ xn8, const unsigned char* __restrict__ cn8,
    const float* __restrict__ xs, const float* __restrict__ cs,
    const float* __restrict__ diag, const float* __restrict__ wp,
    const float* __restrict__ bp, float* __restrict__ partial, int* __restrict__ dummy)
{
  __shared__ char ldsb[2 * LBUF];             // 48 KB

  const int tid = threadIdx.x;
  const int l = tid & 63, w = tid >> 6;       // w in 0..7
  const int swz = (blockIdx.x & 7) * (NRB * NCB / 8) + (blockIdx.x >> 3);
  const int rb = swz >> 4, cb = swz & 15;
  const int rowbase = rb * BM, colbase = cb * BN;

  int4v acc1[4][4];
#pragma unroll
  for (int i = 0; i < 4; ++i)
#pragma unroll
    for (int j = 0; j < 4; ++j)
#pragma unroll
      for (int e = 0; e < 4; ++e) acc1[i][j][e] = 0;

  const int sR = l >> 2;
  const int sC16 = (((l & 3) ^ ((l >> 3) & 3)) << 4);

  const int wr = w >> 1, wc = w & 1;
  const int lr = l & 15, lq = l >> 4;
  int aRel[4], bRel[4];
#pragma unroll
  for (int f = 0; f < 4; ++f) {
    aRel[f] = ((wr * 64 + f * 16 + lr) << 6) + ((lq ^ ((lr >> 1) & 3)) << 4);
    bRel[f] = 16384 + ((wc * 64 + f * 16 + lr) << 6) + ((lq ^ ((lr >> 1) & 3)) << 4);
  }

#define STAGE(buf, kcn) do {                                                   \
    char* dst_ = ldsb + (buf) * LBUF;                                          \
    _Pragma("unroll")                                                          \
    for (int q_ = 0; q_ < 3; ++q_) {                                           \
      const int i_ = w * 3 + q_;                                               \
      const bool isA_ = i_ < 16;                                               \
      const int ri_ = isA_ ? i_ : i_ - 16;                                     \
      const unsigned char* src_ = isA_ ? xn8 : cn8;                            \
      const int base_ = isA_ ? rowbase : colbase;                              \
      const size_t go_ = (size_t)(base_ + ri_ * 16 + sR) * DIM + (size_t)(kcn) * BK + sC16; \
      gload_lds16(src_ + go_, dst_ + (isA_ ? 0 : 16384) + ri_ * 1024);         \
    }                                                                          \
  } while (0)

  STAGE(0, 0);

  for (int kc = 0; kc < NKC; ++kc) {
    const int cur = kc & 1;
    if (kc < NKC - 1) {
      STAGE(cur ^ 1, kc + 1);
      asm volatile("s_waitcnt vmcnt(3)" ::: "memory");
    } else {
      asm volatile("s_waitcnt vmcnt(0)" ::: "memory");
    }
    __builtin_amdgcn_s_barrier();

    const char* base = ldsb + cur * LBUF;
    int4v ah[4], bh4[4];
#pragma unroll
    for (int f = 0; f < 4; ++f) {
      ah[f]  = *reinterpret_cast<const int4v*>(base + aRel[f]);
      bh4[f] = *reinterpret_cast<const int4v*>(base + bRel[f]);
    }
    __builtin_amdgcn_s_setprio(1);
#pragma unroll
    for (int mf = 0; mf < 4; ++mf)
#pragma unroll
      for (int nf = 0; nf < 4; ++nf)
        acc1[mf][nf] = __builtin_amdgcn_mfma_i32_16x16x64_i8(ah[mf], bh4[nf], acc1[mf][nf], 0, 0, 0);
    __builtin_amdgcn_s_setprio(0);

    if (kc < NKC - 1) {
      asm volatile("s_waitcnt lgkmcnt(0)" ::: "memory");
      __builtin_amdgcn_s_barrier();
    }
  }
#undef STAGE

  if constexpr (V == 1) {
    // NOEPI probe: keep acc live with minimal cost; no epilogue math.
    int s = 0;
#pragma unroll
    for (int i = 0; i < 4; ++i)
#pragma unroll
      for (int j = 0; j < 4; ++j)
#pragma unroll
        for (int e = 0; e < 4; ++e) s += acc1[i][j][e];
    dummy[(size_t)blockIdx.x * 512 + tid] = s;
    return;
  }

  // ---- epilogue (V=0): per-col kf = (L-MFIX)*log2e; carry (se, mx) ----
  const float wv = wp[0], bvb = bp[0];
  const float MFIX = fabsf(wv) + bvb;
  const float L2E = 1.4426950408889634f;
  const float wl2e = wv * L2E, bl2e = (bvb - MFIX) * L2E;
  float xc4[4];
#pragma unroll
  for (int nf = 0; nf < 4; ++nf)
    xc4[nf] = cs[colbase + wc * 64 + nf * 16 + lr];

  float se16[16], mx16[16];
#pragma unroll
  for (int mf = 0; mf < 4; ++mf) {
#pragma unroll
    for (int r = 0; r < 4; ++r) {
      const int p = mf * 4 + r;
      const int row = rowbase + wr * 64 + mf * 16 + lq * 4 + r;
      const float xsr = xs[row];
      const int tcol = row / GUT - colbase;
      const float dval = diag[row];
      float se = 0.f, mxk = -__builtin_inff();
#pragma unroll
      for (int nf = 0; nf < 4; ++nf) {
        const int coll = wc * 64 + nf * 16 + lr;
        float s = (xsr * xc4[nf]) * (float)acc1[mf][nf][r];
        s = (coll == tcol) ? dval : s;
        s = fmaxf(s, 1e-6f);
        const float kf = fmaf(s, wl2e, bl2e);
        se += exp2f(kf);
        mxk = fmaxf(mxk, kf);
      }
      se16[p] = se; mx16[p] = mxk;
    }
  }

  float seA[8], mxA[8];
  {
    const bool b = lr & 1;
#pragma unroll
    for (int j = 0; j < 8; ++j) {
      seA[j] = (b ? se16[2*j+1] : se16[2*j]) + __shfl_xor(b ? se16[2*j] : se16[2*j+1], 1);
      mxA[j] = fmaxf(b ? mx16[2*j+1] : mx16[2*j], __shfl_xor(b ? mx16[2*j] : mx16[2*j+1], 1));
    }
  }
  float seB[4], mxB[4];
  {
    const bool b = (lr >> 1) & 1;
#pragma unroll
    for (int j = 0; j < 4; ++j) {
      seB[j] = (b ? seA[2*j+1] : seA[2*j]) + __shfl_xor(b ? seA[2*j] : seA[2*j+1], 2);
      mxB[j] = fmaxf(b ? mxA[2*j+1] : mxA[2*j], __shfl_xor(b ? mxA[2*j] : mxA[2*j+1], 2));
    }
  }
  float seC[2], mxC[2];
  {
    const bool b = (lr >> 2) & 1;
#pragma unroll
    for (int j = 0; j < 2; ++j) {
      seC[j] = (b ? seB[2*j+1] : seB[2*j]) + __shfl_xor(b ? seB[2*j] : seB[2*j+1], 4);
      mxC[j] = fmaxf(b ? mxB[2*j+1] : mxB[2*j], __shfl_xor(b ? mxB[2*j] : mxB[2*j+1], 4));
    }
  }
  float seF, mxF;
  {
    const bool b = (lr >> 3) & 1;
    seF = (b ? seC[1] : seC[0]) + __shfl_xor(b ? seC[0] : seC[1], 8);
    mxF = fmaxf(b ? mxC[1] : mxC[0], __shfl_xor(b ? mxC[0] : mxC[1], 8));
  }
  {
    const int prow = rowbase + wr * 64 + (lr >> 2) * 16 + lq * 4 + (lr & 3);
    float2 slot; slot.x = seF; slot.y = mxF;
    *reinterpret_cast<float2*>(partial + ((size_t)(cb * 2 + wc) * NG + prow) * 2) = slot;
  }
}

// ---------------- Kernel 3: merge partials + block-level reduction (80 pairs out) ----------------
__global__ __launch_bounds__(256) void k3_rows(const float* __restrict__ partial,
    const float* __restrict__ diag, const float* __restrict__ wp,
    const float* __restrict__ bp, float* __restrict__ bsum)
{
  const int row = blockIdx.x * 256 + threadIdx.x;
  float se = 0.f, mx = -__builtin_inff();
#pragma unroll
  for (int c = 0; c < NHB; ++c) {
    const float2 v = *reinterpret_cast<const float2*>(partial + ((size_t)c * NG + row) * 2);
    se += v.x;
    mx = fmaxf(mx, v.y);
  }
  const float wv = wp[0], bvb = bp[0];
  const float MFIX = fabsf(wv) + bvb;
  const float L2E = 1.4426950408889634f;
  const float wl2e = wv * L2E, bl2e = (bvb - MFIX) * L2E;
  const float tg = fmaf(fmaxf(diag[row], 1e-6f), wl2e, bl2e);
  float sl = tg * 0.6931471805599453f - logf(se);
  float sc = (tg >= mx) ? 1.0f : 0.0f;
  for (int off = 32; off > 0; off >>= 1) { sl += __shfl_down(sl, off); sc += __shfl_down(sc, off); }
  __shared__ float ra[4], rb2[4];
  const int lane = threadIdx.x & 63, wid = threadIdx.x >> 6;
  if (lane == 0) { ra[wid] = sl; rb2[wid] = sc; }
  __syncthreads();
  if (threadIdx.x == 0) {
    float2 v; v.x = ra[0] + ra[1] + ra[2] + ra[3];
    v.y = rb2[0] + rb2[1] + rb2[2] + rb2[3];
    *reinterpret_cast<float2*>(bsum + blockIdx.x * 2) = v;
  }
}

// ---------------- Kernel 4: final scalar reduction (80 pairs) ----------------
__global__ __launch_bounds__(128) void k4_reduce(const float* __restrict__ bsum,
    float* __restrict__ out)
{
  const int t = threadIdx.x;
  float sl = 0.f, sc = 0.f;
  if (t < K3B) {
    const float2 v = *reinterpret_cast<const float2*>(bsum + t * 2);
    sl = v.x; sc = v.y;
  }
  for (int off = 32; off > 0; off >>= 1) { sl += __shfl_down(sl, off); sc += __shfl_down(sc, off); }
  __shared__ float ra[2], rb2[2];
  const int lane = t & 63, wid = t >> 6;
  if (lane == 0) { ra[wid] = sl; rb2[wid] = sc; }
  __syncthreads();
  if (t == 0) {
    const float S = ra[0] + ra[1];
    const float C = rb2[0] + rb2[1];
    out[0] = -(S * (1.0f / NG));
    out[1] = C * (100.0f / NG);
  }
}

extern "C" void kernel_launch(void* const* d_in, const int* in_sizes, int n_in,
                              void* d_out, int out_size, void* d_ws, size_t ws_size,
                              hipStream_t stream)
{
  const float* x = (const float*)d_in[0];
  const float* w = (const float*)d_in[1];
  const float* b = (const float*)d_in[2];
  float* out = (float*)d_out;

  char* ws = (char*)d_ws;
  unsigned char* xn8 = (unsigned char*)ws;                            // NG*512 i8
  unsigned char* cn8 = (unsigned char*)(ws + (size_t)NG * DIM);       // NSPK*512 i8
  char* after = ws + (size_t)NG * DIM + (size_t)NSPK * DIM;
  float* xs   = (float*)after;                                        // NG
  float* cs   = xs + NG;                                              // NSPK
  float* diag = cs + NSPK;                                            // NG
  float* part = diag + NG;                                            // NHB*NG*2
  float* bsum = part + (size_t)NHB * NG * 2;                          // K3B*2
  int*   dumy = (int*)(bsum + K3B * 2 + 16);                          // 1280*512 i32 probe sink

  hipLaunchKernelGGL(k1_prep, dim3(NSPK / 4), dim3(256), 0, stream,
                     x, xn8, cn8, xs, cs, diag);
  hipLaunchKernelGGL((k2_mfma<0>), dim3(NRB * NCB), dim3(512), 0, stream,
                     xn8, cn8, xs, cs, diag, w, b, part, dumy);
  hipLaunchKernelGGL(k3_rows, dim3(K3B), dim3(256), 0, stream, part, diag, w, b, bsum);
  hipLaunchKernelGGL(k4_reduce, dim3(1), dim3(128), 0, stream, bsum, out);

  // ---- NOEPI ablation probes (x3 for SNR): t_noepi = (dur_us - ~61)/3 ----
  hipLaunchKernelGGL((k2_mfma<1>), dim3(NRB * NCB), dim3(512), 0, stream,
                     xn8, cn8, xs, cs, diag, w, b, part, dumy);
  hipLaunchKernelGGL((k2_mfma<1>), dim3(NRB * NCB), dim3(512), 0, stream,
                     xn8, cn8, xs, cs, diag, w, b, part, dumy);
  hipLaunchKernelGGL((k2_mfma<1>), dim3(NRB * NCB), dim3(512), 0, stream,
                     xn8, cn8, xs, cs, diag, w, b, part, dumy);
}

// Round 18
// 55.984 us; speedup vs baseline: 2.1932x; 2.1932x over previous
//
#include <hip/hip_runtime.h>
#include <math.h>

#define NSPK 2048
#define GUT  10
#define DIM  512
#define NG   (NSPK*GUT)

#define BM 256
#define BN 128
#define BK 64
#define NCB (NSPK/BN)   // 16 column blocks
#define NHB (NCB*2)     // 32 column half-blocks (64 cols each)
#define NRB (NG/BM)     // 80 row blocks
#define NKC (DIM/BK)    // 8 K-iterations
#define K3B (NG/256)    // 80 k3 blocks
#define LBUF 24576      // 24 KB per LDS buffer: A[256][64]=16K + B[128][64]=8K

typedef __attribute__((ext_vector_type(4))) int int4v;

__device__ inline void gload_lds16(const void* g, void* l) {
  __builtin_amdgcn_global_load_lds(
      (const __attribute__((address_space(1))) void*)g,
      (__attribute__((address_space(3))) void*)l, 16, 0, 0);
}

// Raw v_exp_f32: our kf domain is [-14.5, 0] -> exp2 in [4e-5,1], no denormals,
// so the OCML range-handling expansion (~6 ops) is dead weight.
__device__ __forceinline__ float exp2_fast(float x) {
#if __has_builtin(__builtin_amdgcn_exp2f)
  return __builtin_amdgcn_exp2f(x);
#else
  float r;
  asm("v_exp_f32 %0, %1" : "=v"(r) : "v"(x));
  return r;
#endif
}

__device__ __forceinline__ float mergesum(float a, float b, int mask, bool bsel) {
  const float ss = bsel ? a : b;
  const float sk = bsel ? b : a;
  return sk + __shfl_xor(ss, mask);
}
__device__ inline unsigned pack4i8(float a, float b, float c, float d, float qs) {
  const int q0 = (int)rintf(a * qs) & 255, q1 = (int)rintf(b * qs) & 255;
  const int q2 = (int)rintf(c * qs) & 255, q3 = (int)rintf(d * qs) & 255;
  return (unsigned)q0 | ((unsigned)q1 << 8) | ((unsigned)q2 << 16) | ((unsigned)q3 << 24);
}

// ---------------- Kernel 1: 4 speakers/block (1 wave each); multi-value butterfly ----------------
__global__ __launch_bounds__(256) void k1_prep(const float* __restrict__ x,
    unsigned char* __restrict__ xn8, unsigned char* __restrict__ cn8,
    float* __restrict__ xs, float* __restrict__ cs, float* __restrict__ diag)
{
  const int n = blockIdx.x * 4 + (threadIdx.x >> 6);
  const int l = threadIdx.x & 63;
  const float* xb = x + (size_t)n * GUT * DIM + l * 8;

  float4 xa[GUT], xc[GUT];
#pragma unroll
  for (int g = 0; g < GUT; ++g) {
    xa[g] = *reinterpret_cast<const float4*>(xb + g * DIM);
    xc[g] = *reinterpret_cast<const float4*>(xb + g * DIM + 4);
  }
  float s0=0,s1=0,s2=0,s3=0,s4=0,s5=0,s6=0,s7=0;
#pragma unroll
  for (int g = 0; g < GUT; ++g) {
    s0 += xa[g].x; s1 += xa[g].y; s2 += xa[g].z; s3 += xa[g].w;
    s4 += xc[g].x; s5 += xc[g].y; s6 += xc[g].z; s7 += xc[g].w;
  }
  float P[GUT], D[GUT];
  float mxa = 0.f;
#pragma unroll
  for (int g = 0; g < GUT; ++g) {
    P[g] = xa[g].x*xa[g].x + xa[g].y*xa[g].y + xa[g].z*xa[g].z + xa[g].w*xa[g].w
         + xc[g].x*xc[g].x + xc[g].y*xc[g].y + xc[g].z*xc[g].z + xc[g].w*xc[g].w;
    D[g] = xa[g].x*s0 + xa[g].y*s1 + xa[g].z*s2 + xa[g].w*s3
         + xc[g].x*s4 + xc[g].y*s5 + xc[g].z*s6 + xc[g].w*s7;
    const float m1 = fmaxf(fmaxf(fabsf(xa[g].x), fabsf(xa[g].y)), fmaxf(fabsf(xa[g].z), fabsf(xa[g].w)));
    const float m2 = fmaxf(fmaxf(fabsf(xc[g].x), fabsf(xc[g].y)), fmaxf(fabsf(xc[g].z), fabsf(xc[g].w)));
    mxa = fmaxf(mxa, fmaxf(m1, m2));
  }
  float S = s0*s0+s1*s1+s2*s2+s3*s3+s4*s4+s5*s5+s6*s6+s7*s7;
  float ms = fmaxf(fmaxf(fmaxf(fabsf(s0),fabsf(s1)),fmaxf(fabsf(s2),fabsf(s3))),
                   fmaxf(fmaxf(fabsf(s4),fabsf(s5)),fmaxf(fabsf(s6),fabsf(s7))));

  const bool b0 = l & 1, b1 = l & 2, b2 = l & 4, b3 = l & 8, b4 = l & 16;
  float P01 = mergesum(P[0], P[1], 1, b0);
  float P23 = mergesum(P[2], P[3], 1, b0);
  float P45 = mergesum(P[4], P[5], 1, b0);
  float P67 = mergesum(P[6], P[7], 1, b0);
  float P89 = mergesum(P[8], P[9], 1, b0);
  float D01 = mergesum(D[0], D[1], 1, b0);
  float D23 = mergesum(D[2], D[3], 1, b0);
  float D45 = mergesum(D[4], D[5], 1, b0);
  float D67 = mergesum(D[6], D[7], 1, b0);
  float D89 = mergesum(D[8], D[9], 1, b0);
  S += __shfl_xor(S, 1);
  float PA1 = mergesum(P01, P23, 2, b1);
  float PB1 = mergesum(P45, P67, 2, b1);
  float DA1 = mergesum(D01, D23, 2, b1);
  float DB1 = mergesum(D45, D67, 2, b1);
  P89 += __shfl_xor(P89, 2); D89 += __shfl_xor(D89, 2); S += __shfl_xor(S, 2);
  float PA = mergesum(PA1, PB1, 4, b2);
  float DA = mergesum(DA1, DB1, 4, b2);
  P89 += __shfl_xor(P89, 4); D89 += __shfl_xor(D89, 4); S += __shfl_xor(S, 4);
  float PX = mergesum(PA, P89, 8, b3);
  float DX = mergesum(DA, D89, 8, b3);
  S += __shfl_xor(S, 8);
  float V = mergesum(PX, DX, 16, b4);
  S += __shfl_xor(S, 16);
  V += __shfl_xor(V, 32);
  S += __shfl_xor(S, 32);

#pragma unroll
  for (int m = 1; m < 64; m <<= 1) mxa = fmaxf(mxa, __shfl_xor(mxa, m));
#pragma unroll
  for (int m = 1; m < 64; m <<= 1) ms = fmaxf(ms, __shfl_xor(ms, m));

  const float pdv = __shfl(V, l + 16);

  const float qs = 127.0f / mxa;
#pragma unroll
  for (int g = 0; g < GUT; ++g) {
    uint2 v; v.x = pack4i8(xa[g].x, xa[g].y, xa[g].z, xa[g].w, qs);
             v.y = pack4i8(xc[g].x, xc[g].y, xc[g].z, xc[g].w, qs);
    reinterpret_cast<uint2*>(xn8)[((size_t)n * GUT + g) * 64 + l] = v;
  }
  const float qsc = 127.0f / ms;
  {
    uint2 cp; cp.x = pack4i8(s0, s1, s2, s3, qsc); cp.y = pack4i8(s4, s5, s6, s7, qsc);
    reinterpret_cast<uint2*>(cn8)[n * 64 + l] = cp;
  }

  if (l < GUT) {
    const float psq = V, pd = pdv;
    const float dxe = (pd - psq) * (1.0f / (GUT - 1));
    float ne2 = (S - 2.f * pd + psq) * (1.0f / ((GUT - 1) * (GUT - 1)));
    ne2 = fmaxf(ne2, 0.f);
    const float rn = fmaxf(sqrtf(psq), 1e-8f);
    diag[n * GUT + l] = dxe / (rn * fmaxf(sqrtf(ne2), 1e-8f));
    xs[n * GUT + l] = mxa / (127.0f * rn);
  }
  if (l == 0) {
    const float cnorm  = sqrtf(S) * (1.0f / GUT);
    const float cscale = (1.0f / GUT) / fmaxf(cnorm, 1e-8f);
    cs[n] = cscale * ms * (1.0f / 127.0f);
  }
}

// ---------------- Kernel 2: BM=256 8-wave dbuf loop (proven) + surgically-lean epilogue ----------------
__global__ __launch_bounds__(512, 4) void k2_mfma(
    const unsigned char* __restrict__ xn8, const unsigned char* __restrict__ cn8,
    const float* __restrict__ xs, const float* __restrict__ cs,
    const float* __restrict__ diag, const float* __restrict__ wp,
    const float* __restrict__ bp, float* __restrict__ partial)
{
  __shared__ char ldsb[2 * LBUF];             // 48 KB

  const int tid = threadIdx.x;
  const int l = tid & 63, w = tid >> 6;       // w in 0..7
  const int swz = (blockIdx.x & 7) * (NRB * NCB / 8) + (blockIdx.x >> 3);
  const int rb = swz >> 4, cb = swz & 15;
  const int rowbase = rb * BM, colbase = cb * BN;

  int4v acc1[4][4];
#pragma unroll
  for (int i = 0; i < 4; ++i)
#pragma unroll
    for (int j = 0; j < 4; ++j)
#pragma unroll
      for (int e = 0; e < 4; ++e) acc1[i][j][e] = 0;

  const int sR = l >> 2;
  const int sC16 = (((l & 3) ^ ((l >> 3) & 3)) << 4);

  const int wr = w >> 1, wc = w & 1;
  const int lr = l & 15, lq = l >> 4;
  int aRel[4], bRel[4];
#pragma unroll
  for (int f = 0; f < 4; ++f) {
    aRel[f] = ((wr * 64 + f * 16 + lr) << 6) + ((lq ^ ((lr >> 1) & 3)) << 4);
    bRel[f] = 16384 + ((wc * 64 + f * 16 + lr) << 6) + ((lq ^ ((lr >> 1) & 3)) << 4);
  }

#define STAGE(buf, kcn) do {                                                   \
    char* dst_ = ldsb + (buf) * LBUF;                                          \
    _Pragma("unroll")                                                          \
    for (int q_ = 0; q_ < 3; ++q_) {                                           \
      const int i_ = w * 3 + q_;                                               \
      const bool isA_ = i_ < 16;                                               \
      const int ri_ = isA_ ? i_ : i_ - 16;                                     \
      const unsigned char* src_ = isA_ ? xn8 : cn8;                            \
      const int base_ = isA_ ? rowbase : colbase;                              \
      const size_t go_ = (size_t)(base_ + ri_ * 16 + sR) * DIM + (size_t)(kcn) * BK + sC16; \
      gload_lds16(src_ + go_, dst_ + (isA_ ? 0 : 16384) + ri_ * 1024);         \
    }                                                                          \
  } while (0)

  STAGE(0, 0);

  for (int kc = 0; kc < NKC; ++kc) {
    const int cur = kc & 1;
    if (kc < NKC - 1) {
      STAGE(cur ^ 1, kc + 1);
      asm volatile("s_waitcnt vmcnt(3)" ::: "memory");
    } else {
      asm volatile("s_waitcnt vmcnt(0)" ::: "memory");
    }
    __builtin_amdgcn_s_barrier();

    const char* base = ldsb + cur * LBUF;
    int4v ah[4], bh4[4];
#pragma unroll
    for (int f = 0; f < 4; ++f) {
      ah[f]  = *reinterpret_cast<const int4v*>(base + aRel[f]);
      bh4[f] = *reinterpret_cast<const int4v*>(base + bRel[f]);
    }
    __builtin_amdgcn_s_setprio(1);
#pragma unroll
    for (int mf = 0; mf < 4; ++mf)
#pragma unroll
      for (int nf = 0; nf < 4; ++nf)
        acc1[mf][nf] = __builtin_amdgcn_mfma_i32_16x16x64_i8(ah[mf], bh4[nf], acc1[mf][nf], 0, 0, 0);
    __builtin_amdgcn_s_setprio(0);

    if (kc < NKC - 1) {
      asm volatile("s_waitcnt lgkmcnt(0)" ::: "memory");
      __builtin_amdgcn_s_barrier();
    }
  }
#undef STAGE

  // ---- epilogue: kf = max(acc*xsr*cw + bl2e, kf0); diag cndmask with kf_d (bit-
  // matches k3's tg); raw v_exp_f32. Carry (se, mx); 30-shuffle butterfly merge. ----
  const float wv = wp[0], bvb = bp[0];
  const float MFIX = fabsf(wv) + bvb;
  const float L2E = 1.4426950408889634f;
  const float wl2e = wv * L2E, bl2e = (bvb - MFIX) * L2E;
  const float kf0 = fmaf(1e-6f, wl2e, bl2e);   // clamped-column logit (bit-matches k3)
  float cw4[4];
#pragma unroll
  for (int nf = 0; nf < 4; ++nf)
    cw4[nf] = cs[colbase + wc * 64 + nf * 16 + lr] * wl2e;

  float se16[16], mx16[16];
#pragma unroll
  for (int mf = 0; mf < 4; ++mf) {
#pragma unroll
    for (int r = 0; r < 4; ++r) {
      const int p = mf * 4 + r;
      const int row = rowbase + wr * 64 + mf * 16 + lq * 4 + r;
      const float xsr = xs[row];
      const int tcol = row / GUT - colbase;
      const float kf_d = fmaf(fmaxf(diag[row], 1e-6f), wl2e, bl2e);  // same ops as k3 tg
      float se = 0.f, mxk = -__builtin_inff();
#pragma unroll
      for (int nf = 0; nf < 4; ++nf) {
        const int coll = wc * 64 + nf * 16 + lr;
        const float t = (float)acc1[mf][nf][r] * xsr;
        float kf = fmaf(t, cw4[nf], bl2e);
        kf = fmaxf(kf, kf0);                    // torch.clamp(min=1e-6) folded
        kf = (coll == tcol) ? kf_d : kf;        // diag substitution
        se += exp2_fast(kf);
        mxk = fmaxf(mxk, kf);
      }
      se16[p] = se; mx16[p] = mxk;
    }
  }

  float seA[8], mxA[8];
  {
    const bool b = lr & 1;
#pragma unroll
    for (int j = 0; j < 8; ++j) {
      seA[j] = (b ? se16[2*j+1] : se16[2*j]) + __shfl_xor(b ? se16[2*j] : se16[2*j+1], 1);
      mxA[j] = fmaxf(b ? mx16[2*j+1] : mx16[2*j], __shfl_xor(b ? mx16[2*j] : mx16[2*j+1], 1));
    }
  }
  float seB[4], mxB[4];
  {
    const bool b = (lr >> 1) & 1;
#pragma unroll
    for (int j = 0; j < 4; ++j) {
      seB[j] = (b ? seA[2*j+1] : seA[2*j]) + __shfl_xor(b ? seA[2*j] : seA[2*j+1], 2);
      mxB[j] = fmaxf(b ? mxA[2*j+1] : mxA[2*j], __shfl_xor(b ? mxA[2*j] : mxA[2*j+1], 2));
    }
  }
  float seC[2], mxC[2];
  {
    const bool b = (lr >> 2) & 1;
#pragma unroll
    for (int j = 0; j < 2; ++j) {
      seC[j] = (b ? seB[2*j+1] : seB[2*j]) + __shfl_xor(b ? seB[2*j] : seB[2*j+1], 4);
      mxC[j] = fmaxf(b ? mxB[2*j+1] : mxB[2*j], __shfl_xor(b ? mxB[2*j] : mxB[2*j+1], 4));
    }
  }
  float seF, mxF;
  {
    const bool b = (lr >> 3) & 1;
    seF = (b ? seC[1] : seC[0]) + __shfl_xor(b ? seC[0] : seC[1], 8);
    mxF = fmaxf(b ? mxC[1] : mxC[0], __shfl_xor(b ? mxC[0] : mxC[1], 8));
  }
  {
    const int prow = rowbase + wr * 64 + (lr >> 2) * 16 + lq * 4 + (lr & 3);
    float2 slot; slot.x = seF; slot.y = mxF;
    *reinterpret_cast<float2*>(partial + ((size_t)(cb * 2 + wc) * NG + prow) * 2) = slot;
  }
}

// ---------------- Kernel 3: merge partials + block-level reduction (80 pairs out) ----------------
__global__ __launch_bounds__(256) void k3_rows(const float* __restrict__ partial,
    const float* __restrict__ diag, const float* __restrict__ wp,
    const float* __restrict__ bp, float* __restrict__ bsum)
{
  const int row = blockIdx.x * 256 + threadIdx.x;
  float se = 0.f, mx = -__builtin_inff();
#pragma unroll
  for (int c = 0; c < NHB; ++c) {
    const float2 v = *reinterpret_cast<const float2*>(partial + ((size_t)c * NG + row) * 2);
    se += v.x;
    mx = fmaxf(mx, v.y);
  }
  const float wv = wp[0], bvb = bp[0];
  const float MFIX = fabsf(wv) + bvb;
  const float L2E = 1.4426950408889634f;
  const float wl2e = wv * L2E, bl2e = (bvb - MFIX) * L2E;
  const float tg = fmaf(fmaxf(diag[row], 1e-6f), wl2e, bl2e);
  float sl = tg * 0.6931471805599453f - logf(se);
  float sc = (tg >= mx) ? 1.0f : 0.0f;
  for (int off = 32; off > 0; off >>= 1) { sl += __shfl_down(sl, off); sc += __shfl_down(sc, off); }
  __shared__ float ra[4], rb2[4];
  const int lane = threadIdx.x & 63, wid = threadIdx.x >> 6;
  if (lane == 0) { ra[wid] = sl; rb2[wid] = sc; }
  __syncthreads();
  if (threadIdx.x == 0) {
    float2 v; v.x = ra[0] + ra[1] + ra[2] + ra[3];
    v.y = rb2[0] + rb2[1] + rb2[2] + rb2[3];
    *reinterpret_cast<float2*>(bsum + blockIdx.x * 2) = v;
  }
}

// ---------------- Kernel 4: final scalar reduction (80 pairs) ----------------
__global__ __launch_bounds__(128) void k4_reduce(const float* __restrict__ bsum,
    float* __restrict__ out)
{
  const int t = threadIdx.x;
  float sl = 0.f, sc = 0.f;
  if (t < K3B) {
    const float2 v = *reinterpret_cast<const float2*>(bsum + t * 2);
    sl = v.x; sc = v.y;
  }
  for (int off = 32; off > 0; off >>= 1) { sl += __shfl_down(sl, off); sc += __shfl_down(sc, off); }
  __shared__ float ra[2], rb2[2];
  const int lane = t & 63, wid = t >> 6;
  if (lane == 0) { ra[wid] = sl; rb2[wid] = sc; }
  __syncthreads();
  if (t == 0) {
    const float S = ra[0] + ra[1];
    const float C = rb2[0] + rb2[1];
    out[0] = -(S * (1.0f / NG));
    out[1] = C * (100.0f / NG);
  }
}

extern "C" void kernel_launch(void* const* d_in, const int* in_sizes, int n_in,
                              void* d_out, int out_size, void* d_ws, size_t ws_size,
                              hipStream_t stream)
{
  const float* x = (const float*)d_in[0];
  const float* w = (const float*)d_in[1];
  const float* b = (const float*)d_in[2];
  float* out = (float*)d_out;

  char* ws = (char*)d_ws;
  unsigned char* xn8 = (unsigned char*)ws;                            // NG*512 i8
  unsigned char* cn8 = (unsigned char*)(ws + (size_t)NG * DIM);       // NSPK*512 i8
  char* after = ws + (size_t)NG * DIM + (size_t)NSPK * DIM;
  float* xs   = (float*)after;                                        // NG
  float* cs   = xs + NG;                                              // NSPK
  float* diag = cs + NSPK;                                            // NG
  float* part = diag + NG;                                            // NHB*NG*2
  float* bsum = part + (size_t)NHB * NG * 2;                          // K3B*2

  hipLaunchKernelGGL(k1_prep, dim3(NSPK / 4), dim3(256), 0, stream,
                     x, xn8, cn8, xs, cs, diag);
  hipLaunchKernelGGL(k2_mfma, dim3(NRB * NCB), dim3(512), 0, stream,
                     xn8, cn8, xs, cs, diag, w, b, part);
  hipLaunchKernelGGL(k3_rows, dim3(K3B), dim3(256), 0, stream, part, diag, w, b, bsum);
  hipLaunchKernelGGL(k4_reduce, dim3(1), dim3(128), 0, stream, bsum, out);
}